// Round 1
// baseline (151.891 us; speedup 1.0000x reference)
//
#include <hip/hip_runtime.h>

constexpr int H = 2048;
constexpr float EPS_ = 1e-6f;

// One block per (b,t) row. 256 threads x 8 elements = 2048 = H.
// Phase 1: read hs[0] row + activated row (stay in registers), accumulate
//   10 partials: sumsq(hs0), sumsq(act), and 4+4 router dot-products.
// Reduce, compute the 5 per-row scalars once, broadcast via LDS.
// Phase 2: read hs[1..3] rows + out_scale, emit output. Each HBM stream
// touched exactly once.
__global__ __launch_bounds__(256) void altup_fused(
    const float* __restrict__ hs,   // [4, R, H]
    const float* __restrict__ act,  // [R, H]
    const float* __restrict__ rnw,  // [H]
    const float* __restrict__ Wr,   // [4, H]
    const float* __restrict__ Wp,   // [16, 4]
    const float* __restrict__ Wc,   // [4, 4]
    const float* __restrict__ osc,  // [H]
    float* __restrict__ out,        // [R, H]
    int R)
{
    const int tid = threadIdx.x;
    const long long rowoff = (long long)blockIdx.x * H;
    const long long aS = (long long)R * H;   // stride between hs "a" slices

    float4 xv[2], av[2];
    float ss0 = 0.f, ss1 = 0.f;
    float d0[4] = {0.f, 0.f, 0.f, 0.f};
    float d1[4] = {0.f, 0.f, 0.f, 0.f};

#pragma unroll
    for (int c = 0; c < 2; ++c) {
        const int h = c * 1024 + tid * 4;
        const float4 x = *(const float4*)(hs + rowoff + h);
        const float4 a = *(const float4*)(act + rowoff + h);
        const float4 w = *(const float4*)(rnw + h);
        xv[c] = x;
        av[c] = a;
        ss0 += x.x * x.x + x.y * x.y + x.z * x.z + x.w * x.w;
        ss1 += a.x * a.x + a.y * a.y + a.z * a.z + a.w * a.w;
        const float xwx = x.x * w.x, xwy = x.y * w.y, xwz = x.z * w.z, xww = x.w * w.w;
        const float awx = a.x * w.x, awy = a.y * w.y, awz = a.z * w.z, aww = a.w * w.w;
#pragma unroll
        for (int i = 0; i < 4; ++i) {
            const float4 wr = *(const float4*)(Wr + i * H + h);
            d0[i] += xwx * wr.x + xwy * wr.y + xwz * wr.z + xww * wr.w;
            d1[i] += awx * wr.x + awy * wr.y + awz * wr.z + aww * wr.w;
        }
    }

    // ---- reduce 10 partials: wave shuffle tree, then LDS across 4 waves ----
    float acc[10] = {ss0, ss1, d0[0], d0[1], d0[2], d0[3], d1[0], d1[1], d1[2], d1[3]};
#pragma unroll
    for (int off = 32; off >= 1; off >>= 1) {
#pragma unroll
        for (int k = 0; k < 10; ++k) acc[k] += __shfl_down(acc[k], off, 64);
    }

    __shared__ float red[4][10];
    __shared__ float bc[5];
    const int wave = tid >> 6;
    if ((tid & 63) == 0) {
#pragma unroll
        for (int k = 0; k < 10; ++k) red[wave][k] = acc[k];
    }
    __syncthreads();

    if (tid == 0) {
        float t[10];
#pragma unroll
        for (int k = 0; k < 10; ++k)
            t[k] = red[0][k] + red[1][k] + red[2][k] + red[3][k];
        const float inv_h = 1.0f / (float)H;
        // rsqrt(mean(x^2)+eps) * (1/H)  (router_input_scale)
        const float rs0 = (1.0f / sqrtf(t[0] * inv_h + EPS_)) * inv_h;
        const float rs1 = (1.0f / sqrtf(t[1] * inv_h + EPS_)) * inv_h;
        float m[4], m2[4];
#pragma unroll
        for (int i = 0; i < 4; ++i) {
            m[i]  = tanhf(rs0 * t[2 + i]);
            m2[i] = tanhf(rs1 * t[6 + i]);
        }
        // C[b,t,0,a] = sum_i m[i] * Wp[a,i]   (row 0 of the j-index)
#pragma unroll
        for (int a = 0; a < 4; ++a) {
            const float c = Wp[a * 4 + 0] * m[0] + Wp[a * 4 + 1] * m[1] +
                            Wp[a * 4 + 2] * m[2] + Wp[a * 4 + 3] * m[3];
            bc[a] = (a == 0) ? (1.0f + c) : c;  // +hs[0] identity term folded in
        }
        // coefs[b,t,0] = sum_i m2[i] * Wc[0,i] + 1
        bc[4] = Wc[0] * m2[0] + Wc[1] * m2[1] + Wc[2] * m2[2] + Wc[3] * m2[3] + 1.0f;
    }
    __syncthreads();

    const float k0 = bc[0], k1 = bc[1], k2 = bc[2], k3 = bc[3], cc = bc[4];

#pragma unroll
    for (int c = 0; c < 2; ++c) {
        const int h = c * 1024 + tid * 4;
        const float4 h1 = *(const float4*)(hs + aS + rowoff + h);
        const float4 h2 = *(const float4*)(hs + 2 * aS + rowoff + h);
        const float4 h3 = *(const float4*)(hs + 3 * aS + rowoff + h);
        const float4 os = *(const float4*)(osc + h);
        float4 p, o;
        p.x = xv[c].x * k0 + h1.x * k1 + h2.x * k2 + h3.x * k3;
        p.y = xv[c].y * k0 + h1.y * k1 + h2.y * k2 + h3.y * k3;
        p.z = xv[c].z * k0 + h1.z * k1 + h2.z * k2 + h3.z * k3;
        p.w = xv[c].w * k0 + h1.w * k1 + h2.w * k2 + h3.w * k3;
        o.x = ((av[c].x - p.x) * cc + p.x) * os.x;
        o.y = ((av[c].y - p.y) * cc + p.y) * os.y;
        o.z = ((av[c].z - p.z) * cc + p.z) * os.z;
        o.w = ((av[c].w - p.w) * cc + p.w) * os.w;
        *(float4*)(out + rowoff + h) = o;
    }
}

extern "C" void kernel_launch(void* const* d_in, const int* in_sizes, int n_in,
                              void* d_out, int out_size, void* d_ws, size_t ws_size,
                              hipStream_t stream) {
    const float* hs  = (const float*)d_in[0];  // hidden_states [4,B,T,H]
    const float* act = (const float*)d_in[1];  // activated     [B,T,H]
    const float* rnw = (const float*)d_in[2];  // router_norm_w [H]
    const float* Wr  = (const float*)d_in[3];  // W_router      [4,H]
    const float* Wp  = (const float*)d_in[4];  // Wp            [16,4]
    const float* Wc  = (const float*)d_in[5];  // Wc            [4,4]
    const float* osc = (const float*)d_in[6];  // out_scale     [H]
    float* out = (float*)d_out;

    const int R = in_sizes[1] / H;  // B*T rows
    altup_fused<<<R, 256, 0, stream>>>(hs, act, rnw, Wr, Wp, Wc, osc, out, R);
}

// Round 3
// 140.999 us; speedup vs baseline: 1.0772x; 1.0772x over previous
//
#include <hip/hip_runtime.h>

constexpr int H = 2048;
constexpr float EPS_ = 1e-6f;

typedef float f4 __attribute__((ext_vector_type(4)));  // clang vector: OK for nontemporal builtins

// One block per (b,t) row. 256 threads x 8 elements = 2048 = H.
// ALL global loads (7 streams) are issued before the cross-wave reduction,
// so the post-barrier path is pure register math + store. Big streams
// (hs[0..3], act, out) are nontemporal; small reused vectors (rnw, Wr, osc)
// go through the cache hierarchy.
__global__ __launch_bounds__(256) void altup_fused(
    const float* __restrict__ hs,   // [4, R, H]
    const float* __restrict__ act,  // [R, H]
    const float* __restrict__ rnw,  // [H]
    const float* __restrict__ Wr,   // [4, H]
    const float* __restrict__ Wp,   // [16, 4]
    const float* __restrict__ Wc,   // [4, 4]
    const float* __restrict__ osc,  // [H]
    float* __restrict__ out,        // [R, H]
    int R)
{
    const int tid = threadIdx.x;
    const long long rowoff = (long long)blockIdx.x * H;
    const long long aS = (long long)R * H;   // stride between hs "a" slices

    f4 xv[2], av[2], wv[2], h1v[2], h2v[2], h3v[2], ov[2];

    // ---- issue every global load up front (overlaps reduce latency) ----
#pragma unroll
    for (int c = 0; c < 2; ++c) {
        const int h = c * 1024 + tid * 4;
        xv[c]  = __builtin_nontemporal_load((const f4*)(hs + rowoff + h));
        av[c]  = __builtin_nontemporal_load((const f4*)(act + rowoff + h));
        h1v[c] = __builtin_nontemporal_load((const f4*)(hs + aS + rowoff + h));
        h2v[c] = __builtin_nontemporal_load((const f4*)(hs + 2 * aS + rowoff + h));
        h3v[c] = __builtin_nontemporal_load((const f4*)(hs + 3 * aS + rowoff + h));
        wv[c]  = *(const f4*)(rnw + h);
        ov[c]  = *(const f4*)(osc + h);
    }

    float ss0 = 0.f, ss1 = 0.f;
    float d0[4] = {0.f, 0.f, 0.f, 0.f};
    float d1[4] = {0.f, 0.f, 0.f, 0.f};

#pragma unroll
    for (int c = 0; c < 2; ++c) {
        const int h = c * 1024 + tid * 4;
        const f4 x = xv[c], a = av[c], w = wv[c];
        ss0 += x.x * x.x + x.y * x.y + x.z * x.z + x.w * x.w;
        ss1 += a.x * a.x + a.y * a.y + a.z * a.z + a.w * a.w;
        const float xwx = x.x * w.x, xwy = x.y * w.y, xwz = x.z * w.z, xww = x.w * w.w;
        const float awx = a.x * w.x, awy = a.y * w.y, awz = a.z * w.z, aww = a.w * w.w;
#pragma unroll
        for (int i = 0; i < 4; ++i) {
            const f4 wr = *(const f4*)(Wr + i * H + h);
            d0[i] += xwx * wr.x + xwy * wr.y + xwz * wr.z + xww * wr.w;
            d1[i] += awx * wr.x + awy * wr.y + awz * wr.z + aww * wr.w;
        }
    }

    // ---- reduce 10 partials: wave shuffle tree, then LDS across 4 waves ----
    float acc[10] = {ss0, ss1, d0[0], d0[1], d0[2], d0[3], d1[0], d1[1], d1[2], d1[3]};
#pragma unroll
    for (int off = 32; off >= 1; off >>= 1) {
#pragma unroll
        for (int k = 0; k < 10; ++k) acc[k] += __shfl_down(acc[k], off, 64);
    }

    __shared__ float red[4][10];
    __shared__ float bc[5];
    const int wave = tid >> 6;
    if ((tid & 63) == 0) {
#pragma unroll
        for (int k = 0; k < 10; ++k) red[wave][k] = acc[k];
    }
    __syncthreads();

    if (tid == 0) {
        float t[10];
#pragma unroll
        for (int k = 0; k < 10; ++k)
            t[k] = red[0][k] + red[1][k] + red[2][k] + red[3][k];
        const float inv_h = 1.0f / (float)H;
        const float rs0 = (1.0f / sqrtf(t[0] * inv_h + EPS_)) * inv_h;
        const float rs1 = (1.0f / sqrtf(t[1] * inv_h + EPS_)) * inv_h;
        float m[4], m2[4];
#pragma unroll
        for (int i = 0; i < 4; ++i) {
            m[i]  = tanhf(rs0 * t[2 + i]);
            m2[i] = tanhf(rs1 * t[6 + i]);
        }
        // C[b,t,0,a] = sum_i m[i] * Wp[a,i]; +hs[0] identity folded into a==0
#pragma unroll
        for (int a = 0; a < 4; ++a) {
            const float c = Wp[a * 4 + 0] * m[0] + Wp[a * 4 + 1] * m[1] +
                            Wp[a * 4 + 2] * m[2] + Wp[a * 4 + 3] * m[3];
            bc[a] = (a == 0) ? (1.0f + c) : c;
        }
        bc[4] = Wc[0] * m2[0] + Wc[1] * m2[1] + Wc[2] * m2[2] + Wc[3] * m2[3] + 1.0f;
    }
    __syncthreads();

    const float k0 = bc[0], k1 = bc[1], k2 = bc[2], k3 = bc[3], cc = bc[4];

#pragma unroll
    for (int c = 0; c < 2; ++c) {
        const int h = c * 1024 + tid * 4;
        f4 p, o;
        p.x = xv[c].x * k0 + h1v[c].x * k1 + h2v[c].x * k2 + h3v[c].x * k3;
        p.y = xv[c].y * k0 + h1v[c].y * k1 + h2v[c].y * k2 + h3v[c].y * k3;
        p.z = xv[c].z * k0 + h1v[c].z * k1 + h2v[c].z * k2 + h3v[c].z * k3;
        p.w = xv[c].w * k0 + h1v[c].w * k1 + h2v[c].w * k2 + h3v[c].w * k3;
        o.x = ((av[c].x - p.x) * cc + p.x) * ov[c].x;
        o.y = ((av[c].y - p.y) * cc + p.y) * ov[c].y;
        o.z = ((av[c].z - p.z) * cc + p.z) * ov[c].z;
        o.w = ((av[c].w - p.w) * cc + p.w) * ov[c].w;
        __builtin_nontemporal_store(o, (f4*)(out + rowoff + h));
    }
}

extern "C" void kernel_launch(void* const* d_in, const int* in_sizes, int n_in,
                              void* d_out, int out_size, void* d_ws, size_t ws_size,
                              hipStream_t stream) {
    const float* hs  = (const float*)d_in[0];  // hidden_states [4,B,T,H]
    const float* act = (const float*)d_in[1];  // activated     [B,T,H]
    const float* rnw = (const float*)d_in[2];  // router_norm_w [H]
    const float* Wr  = (const float*)d_in[3];  // W_router      [4,H]
    const float* Wp  = (const float*)d_in[4];  // Wp            [16,4]
    const float* Wc  = (const float*)d_in[5];  // Wc            [4,4]
    const float* osc = (const float*)d_in[6];  // out_scale     [H]
    float* out = (float*)d_out;

    const int R = in_sizes[1] / H;  // B*T rows
    altup_fused<<<R, 256, 0, stream>>>(hs, act, rnw, Wr, Wp, Wc, osc, out, R);
}